// Round 14
// baseline (827.087 us; speedup 1.0000x reference)
//
#include <hip/hip_runtime.h>
#include <cstdint>
#include <cstddef>

static constexpr int NN = 24000;   // nodes
static constexpr int NE = 96000;   // edges
static constexpr int NB = 1200;    // graphs
static constexpr int NPG = 20;     // nodes per graph
static constexpr int MPAD = 24064; // NN padded to 128

typedef __attribute__((ext_vector_type(8))) short bfv8;
typedef __attribute__((ext_vector_type(4))) float fv4;

__device__ __forceinline__ unsigned short f2bf(float f){
  unsigned u = __float_as_uint(f);
  u += 0x7FFFu + ((u >> 16) & 1u);   // RNE
  return (unsigned short)(u >> 16);
}
__device__ __forceinline__ float bf2f(unsigned short s){
  return __uint_as_float(((unsigned)s) << 16);
}

// ---------------- CSR build ----------------
__global__ __launch_bounds__(256) void count_kernel(const int* __restrict__ dst,
                                                    unsigned* __restrict__ deg)
{
  int e = blockIdx.x*256 + threadIdx.x;
  if (e < NE) atomicAdd(&deg[dst[e]], 1u);
}

__global__ __launch_bounds__(1024) void scan_kernel(const unsigned* __restrict__ deg,
                                                    unsigned* __restrict__ rowstart)
{
  __shared__ unsigned s[1024];
  __shared__ unsigned carry_s;
  int tid = threadIdx.x;
  if (tid == 0) carry_s = 0;
  __syncthreads();
  for (int base = 0; base < NN; base += 1024){
    unsigned v = (base + tid < NN) ? deg[base + tid] : 0u;
    s[tid] = v;
    __syncthreads();
#pragma unroll
    for (int off = 1; off < 1024; off <<= 1){
      unsigned t = (tid >= off) ? s[tid - off] : 0u;
      __syncthreads();
      s[tid] += t;
      __syncthreads();
    }
    unsigned carry = carry_s;
    if (base + tid < NN) rowstart[base + tid] = carry + s[tid] - v;
    __syncthreads();
    if (tid == 0) carry_s = carry + s[1023];
    __syncthreads();
  }
  if (tid == 0) rowstart[NN] = carry_s;
}

__global__ __launch_bounds__(256) void scatter_kernel(const int* __restrict__ dst,
                                                      const unsigned* __restrict__ rowstart,
                                                      unsigned* __restrict__ cur,
                                                      int* __restrict__ eidx)
{
  int e = blockIdx.x*256 + threadIdx.x;
  if (e >= NE) return;
  int d = dst[e];
  unsigned p = rowstart[d] + atomicAdd(&cur[d], 1u);
  eidx[p] = e;
}

// ---------------- layer-1 node projections (K=9), two outputs per pass ----------------
template<bool BA, bool BB>
__global__ __launch_bounds__(256) void node_gemm_l1_pair(
    const float* __restrict__ x,
    const float* __restrict__ Wa, const float* __restrict__ ba,
    const float* __restrict__ Wb, const float* __restrict__ bb,
    void* __restrict__ outa, void* __restrict__ outb)
{
  int t = blockIdx.x*256 + threadIdx.x;
  if (t >= NN*512) return;
  int n = t >> 9, j = t & 511;
  float xr[9];
#pragma unroll
  for (int i=0;i<9;i++) xr[i] = x[n*9+i];
  float aa=ba[j], ab=bb[j];
#pragma unroll
  for (int i=0;i<9;i++){
    float xi = xr[i];
    aa += xi*Wa[i*512+j];
    ab += xi*Wb[i*512+j];
  }
  if (BA) ((unsigned short*)outa)[t] = f2bf(aa); else ((float*)outa)[t] = aa;
  if (BB) ((unsigned short*)outb)[t] = f2bf(ab); else ((float*)outb)[t] = ab;
}

// ---- fused per-dst-node attention (HC=512): scores + softmax, normalized w out ----
// One wave per dst node. q loaded once; t[c]=q·We computed once; in-wave softmax.
__global__ __launch_bounds__(256) void alpha_fused512(
    const unsigned short* __restrict__ q, const unsigned short* __restrict__ k,
    const float* __restrict__ ea, const float* __restrict__ We,
    const int* __restrict__ src,
    const unsigned* __restrict__ rowstart, const int* __restrict__ eidx,
    float* __restrict__ w)
{
  int wave = (blockIdx.x*256 + threadIdx.x) >> 6;
  int lane = threadIdx.x & 63;
  if (wave >= NN) return;
  int n = wave;
  unsigned p0 = rowstart[n], p1 = rowstart[n+1];
  if (p0 == p1) return;
  const float scale = 0.088388347648318447f;   // 1/sqrt(128)
  int off = lane*8;
  bfv8 qv = *reinterpret_cast<const bfv8*>(q + (size_t)n*512 + off);
  // tproj: t[c] for this lane-group's head
  float t0=0.f,t1=0.f,t2=0.f,t3=0.f;
#pragma unroll
  for (int j=0;j<8;j++){
    float qf = bf2f((unsigned short)qv[j]);
    int f = off + j;
    t0 += qf*We[f]; t1 += qf*We[512+f]; t2 += qf*We[1024+f]; t3 += qf*We[1536+f];
  }
#pragma unroll
  for (int o=8;o>=1;o>>=1){
    t0 += __shfl_xor(t0,o); t1 += __shfl_xor(t1,o);
    t2 += __shfl_xor(t2,o); t3 += __shfl_xor(t3,o);
  }
  bool el = (lane & 15) == 0;
  int h = lane >> 4;
  float mx = -__builtin_inff();
  for (unsigned pp = p0; pp < p1; ++pp){
    int e = eidx[pp];
    int s = src[e];
    bfv8 kv = *reinterpret_cast<const bfv8*>(k + (size_t)s*512 + off);
    float part = 0.f;
#pragma unroll
    for (int j=0;j<8;j++)
      part += bf2f((unsigned short)qv[j]) * bf2f((unsigned short)kv[j]);
#pragma unroll
    for (int o=8;o>=1;o>>=1) part += __shfl_xor(part,o);
    if (el){
      float4 eav = *reinterpret_cast<const float4*>(ea + (size_t)e*4);
      float a = (part + eav.x*t0 + eav.y*t1 + eav.z*t2 + eav.w*t3)*scale;
      w[e*4+h] = a;
      mx = fmaxf(mx, a);
    }
  }
  if (el){
    float sum = 0.f;
    for (unsigned pp = p0; pp < p1; ++pp){
      int e = eidx[pp];
      float ex = __expf(w[e*4+h] - mx);
      w[e*4+h] = ex;
      sum += ex;
    }
    float r = 1.0f / (sum + 1e-16f);
    for (unsigned pp = p0; pp < p1; ++pp){
      int e = eidx[pp];
      w[e*4+h] *= r;
    }
  }
}

// ---- fused per-dst-node attention (HC=1024) ----
__global__ __launch_bounds__(256) void alpha_fused1024(
    const unsigned short* __restrict__ q, const unsigned short* __restrict__ k,
    const float* __restrict__ ea, const float* __restrict__ We,
    const int* __restrict__ src,
    const unsigned* __restrict__ rowstart, const int* __restrict__ eidx,
    float* __restrict__ w)
{
  int wave = (blockIdx.x*256 + threadIdx.x) >> 6;
  int lane = threadIdx.x & 63;
  if (wave >= NN) return;
  int n = wave;
  unsigned p0 = rowstart[n], p1 = rowstart[n+1];
  if (p0 == p1) return;
  const float scale = 1.0f/16.0f;   // 1/sqrt(256)
  int off = lane*8;
  bfv8 qv0 = *reinterpret_cast<const bfv8*>(q + (size_t)n*1024 + off);
  bfv8 qv1 = *reinterpret_cast<const bfv8*>(q + (size_t)n*1024 + 512 + off);
  // tproj for both half-heads
  float a0=0.f,a1=0.f,a2=0.f,a3=0.f, b0=0.f,b1=0.f,b2=0.f,b3=0.f;
#pragma unroll
  for (int j=0;j<8;j++){
    float q0 = bf2f((unsigned short)qv0[j]);
    float q1 = bf2f((unsigned short)qv1[j]);
    int f0 = off + j, f1 = 512 + off + j;
    a0 += q0*We[f0];      a1 += q0*We[1024+f0];
    a2 += q0*We[2048+f0]; a3 += q0*We[3072+f0];
    b0 += q1*We[f1];      b1 += q1*We[1024+f1];
    b2 += q1*We[2048+f1]; b3 += q1*We[3072+f1];
  }
#pragma unroll
  for (int o=16;o>=1;o>>=1){
    a0 += __shfl_xor(a0,o); a1 += __shfl_xor(a1,o);
    a2 += __shfl_xor(a2,o); a3 += __shfl_xor(a3,o);
    b0 += __shfl_xor(b0,o); b1 += __shfl_xor(b1,o);
    b2 += __shfl_xor(b2,o); b3 += __shfl_xor(b3,o);
  }
  bool el = (lane & 31) == 0;
  int hg = lane >> 5;             // 0 or 1
  int h0 = hg, h1 = 2 + hg;       // heads for half0/half1
  float mx0 = -__builtin_inff(), mx1 = -__builtin_inff();
  for (unsigned pp = p0; pp < p1; ++pp){
    int e = eidx[pp];
    int s = src[e];
    bfv8 kv0 = *reinterpret_cast<const bfv8*>(k + (size_t)s*1024 + off);
    bfv8 kv1 = *reinterpret_cast<const bfv8*>(k + (size_t)s*1024 + 512 + off);
    float p0f = 0.f, p1f = 0.f;
#pragma unroll
    for (int j=0;j<8;j++){
      p0f += bf2f((unsigned short)qv0[j]) * bf2f((unsigned short)kv0[j]);
      p1f += bf2f((unsigned short)qv1[j]) * bf2f((unsigned short)kv1[j]);
    }
#pragma unroll
    for (int o=16;o>=1;o>>=1){
      p0f += __shfl_xor(p0f,o);
      p1f += __shfl_xor(p1f,o);
    }
    if (el){
      float4 eav = *reinterpret_cast<const float4*>(ea + (size_t)e*4);
      float s0 = (p0f + eav.x*a0 + eav.y*a1 + eav.z*a2 + eav.w*a3)*scale;
      float s1 = (p1f + eav.x*b0 + eav.y*b1 + eav.z*b2 + eav.w*b3)*scale;
      w[e*4+h0] = s0;
      w[e*4+h1] = s1;
      mx0 = fmaxf(mx0, s0);
      mx1 = fmaxf(mx1, s1);
    }
  }
  if (el){
    float sum0 = 0.f, sum1 = 0.f;
    for (unsigned pp = p0; pp < p1; ++pp){
      int e = eidx[pp];
      float e0 = __expf(w[e*4+h0] - mx0);
      float e1 = __expf(w[e*4+h1] - mx1);
      w[e*4+h0] = e0; w[e*4+h1] = e1;
      sum0 += e0; sum1 += e1;
    }
    float r0 = 1.0f/(sum0 + 1e-16f), r1 = 1.0f/(sum1 + 1e-16f);
    for (unsigned pp = p0; pp < p1; ++pp){
      int e = eidx[pp];
      w[e*4+h0] *= r0;
      w[e*4+h1] *= r1;
    }
  }
}

// ---------------- CSR gather L1: bf16 v, bf16 s1 init, bf16 relu'd output ----------------
__global__ __launch_bounds__(256) void gather512_kernel(
    const unsigned short* __restrict__ v, const float* __restrict__ ea,
    const float* __restrict__ We,
    const int* __restrict__ src,
    const unsigned* __restrict__ rowstart, const int* __restrict__ eidx,
    const float* __restrict__ wgt,
    const unsigned short* __restrict__ accin, unsigned short* __restrict__ hb)
{
  int n = blockIdx.x;
  int tid = threadIdx.x;
  int h = tid >> 6;
  int f2 = tid*2;
  unsigned p0 = rowstart[n], p1 = rowstart[n+1];
  float2 W0 = *reinterpret_cast<const float2*>(We + 0*512 + f2);
  float2 W1 = *reinterpret_cast<const float2*>(We + 1*512 + f2);
  float2 W2 = *reinterpret_cast<const float2*>(We + 2*512 + f2);
  float2 W3 = *reinterpret_cast<const float2*>(We + 3*512 + f2);
  ushort2 a0 = *reinterpret_cast<const ushort2*>(accin + (size_t)n*512 + f2);
  float2 s = make_float2(bf2f(a0.x), bf2f(a0.y));
  for (unsigned p = p0; p < p1; ++p){
    int e  = eidx[p];
    float w = wgt[e*4+h];
    float4 eav = *reinterpret_cast<const float4*>(ea + (size_t)e*4);
    ushort2 vv = *reinterpret_cast<const ushort2*>(v + (size_t)src[e]*512 + f2);
    float efx = eav.x*W0.x + eav.y*W1.x + eav.z*W2.x + eav.w*W3.x;
    float efy = eav.x*W0.y + eav.y*W1.y + eav.z*W2.y + eav.w*W3.y;
    s.x += w*(bf2f(vv.x) + efx);
    s.y += w*(bf2f(vv.y) + efy);
  }
  ushort2 o;
  o.x = f2bf(fmaxf(s.x, 0.0f));
  o.y = f2bf(fmaxf(s.y, 0.0f));
  *reinterpret_cast<ushort2*>(hb + (size_t)n*512 + f2) = o;
}

// ---------------- CSR gather L2: bf16 v, bf16 acc RMW (fp32 accumulate) ----------------
__global__ __launch_bounds__(256) void gather1024_kernel(
    const unsigned short* __restrict__ v, const float* __restrict__ ea,
    const float* __restrict__ We,
    const int* __restrict__ src,
    const unsigned* __restrict__ rowstart, const int* __restrict__ eidx,
    const float* __restrict__ wgt,
    unsigned short* __restrict__ acc)
{
  int n = blockIdx.x;
  int tid = threadIdx.x;
  int h = tid >> 6;
  int f4 = tid*4;
  unsigned p0 = rowstart[n], p1 = rowstart[n+1];
  float4 W0 = *reinterpret_cast<const float4*>(We + 0*1024 + f4);
  float4 W1 = *reinterpret_cast<const float4*>(We + 1*1024 + f4);
  float4 W2 = *reinterpret_cast<const float4*>(We + 2*1024 + f4);
  float4 W3 = *reinterpret_cast<const float4*>(We + 3*1024 + f4);
  ushort4 a0 = *reinterpret_cast<const ushort4*>(acc + (size_t)n*1024 + f4);
  float4 s = make_float4(bf2f(a0.x), bf2f(a0.y), bf2f(a0.z), bf2f(a0.w));
  for (unsigned p = p0; p < p1; ++p){
    int e  = eidx[p];
    float w = wgt[e*4+h];
    float4 eav = *reinterpret_cast<const float4*>(ea + (size_t)e*4);
    ushort4 vv = *reinterpret_cast<const ushort4*>(v + (size_t)src[e]*1024 + f4);
    s.x += w*(bf2f(vv.x) + eav.x*W0.x + eav.y*W1.x + eav.z*W2.x + eav.w*W3.x);
    s.y += w*(bf2f(vv.y) + eav.x*W0.y + eav.y*W1.y + eav.z*W2.y + eav.w*W3.y);
    s.z += w*(bf2f(vv.z) + eav.x*W0.z + eav.y*W1.z + eav.z*W2.z + eav.w*W3.z);
    s.w += w*(bf2f(vv.w) + eav.x*W0.w + eav.y*W1.w + eav.z*W2.w + eav.w*W3.w);
  }
  ushort4 o;
  o.x = f2bf(s.x); o.y = f2bf(s.y); o.z = f2bf(s.z); o.w = f2bf(s.w);
  *reinterpret_cast<ushort4*>(acc + (size_t)n*1024 + f4) = o;
}

// ---------------- W[512,1024] -> Wt[1024,512] bf16 ----------------
__global__ __launch_bounds__(256) void cvt_wt_kernel(const float* __restrict__ W,
                                                     unsigned short* __restrict__ Wt)
{
  int t = blockIdx.x*256 + threadIdx.x;
  if (t >= 1024*512) return;
  int n = t >> 9, k = t & 511;
  Wt[t] = f2bf(W[k*1024 + n]);
}

// ---------------- bf16 MFMA GEMM: out[M,1024] = A[MPAD,512]@Wt^T + bias ----------------
template<bool BOUT>
__global__ __launch_bounds__(256) void gemm_bf16_mfma(
    const unsigned short* __restrict__ A,
    const unsigned short* __restrict__ B,   // Wt
    const float* __restrict__ bias,
    void* __restrict__ Cout, int M)
{
  constexpr int K = 512, N = 1024;
  __shared__ unsigned short As[128*32];
  __shared__ unsigned short Bs[128*32];
  int tid  = threadIdx.x;
  int wid  = tid >> 6, lane = tid & 63;
  int wr   = wid >> 1, wc = wid & 1;
  int bm   = blockIdx.y * 128, bn = blockIdx.x * 128;
  int l15  = lane & 15, kg = lane >> 4;

  int r0 = (wid*2+0)*16 + (lane>>2);
  int r1 = (wid*2+1)*16 + (lane>>2);
  int s0 = lane & 3;
  int kc0 = s0 ^ ((r0>>1)&3);
  int kc1 = s0 ^ ((r1>>1)&3);
  unsigned short* ldsA0 = As + (wid*2+0)*512;
  unsigned short* ldsA1 = As + (wid*2+1)*512;
  unsigned short* ldsB0 = Bs + (wid*2+0)*512;
  unsigned short* ldsB1 = Bs + (wid*2+1)*512;

  fv4 acc[4][4];
#pragma unroll
  for (int m=0;m<4;m++)
#pragma unroll
    for (int n=0;n<4;n++) acc[m][n] = (fv4){0.f,0.f,0.f,0.f};

  for (int k0 = 0; k0 < K; k0 += 32){
    __syncthreads();
    __builtin_amdgcn_global_load_lds(
        (const __attribute__((address_space(1))) void*)(A + (size_t)(bm+r0)*K + k0 + kc0*8),
        (__attribute__((address_space(3))) void*)ldsA0, 16, 0, 0);
    __builtin_amdgcn_global_load_lds(
        (const __attribute__((address_space(1))) void*)(A + (size_t)(bm+r1)*K + k0 + kc1*8),
        (__attribute__((address_space(3))) void*)ldsA1, 16, 0, 0);
    __builtin_amdgcn_global_load_lds(
        (const __attribute__((address_space(1))) void*)(B + (size_t)(bn+r0)*K + k0 + kc0*8),
        (__attribute__((address_space(3))) void*)ldsB0, 16, 0, 0);
    __builtin_amdgcn_global_load_lds(
        (const __attribute__((address_space(1))) void*)(B + (size_t)(bn+r1)*K + k0 + kc1*8),
        (__attribute__((address_space(3))) void*)ldsB1, 16, 0, 0);
    __syncthreads();
    bfv8 af[4], bfr[4];
#pragma unroll
    for (int m=0;m<4;m++){
      int r  = wr*64 + m*16 + l15;
      int sl = kg ^ ((r>>1)&3);
      af[m] = *reinterpret_cast<const bfv8*>(reinterpret_cast<char*>(As) + r*64 + sl*16);
    }
#pragma unroll
    for (int n=0;n<4;n++){
      int r  = wc*64 + n*16 + l15;
      int sl = kg ^ ((r>>1)&3);
      bfr[n] = *reinterpret_cast<const bfv8*>(reinterpret_cast<char*>(Bs) + r*64 + sl*16);
    }
#pragma unroll
    for (int m=0;m<4;m++)
#pragma unroll
      for (int n=0;n<4;n++)
        acc[m][n] = __builtin_amdgcn_mfma_f32_16x16x32_bf16(af[m], bfr[n], acc[m][n], 0, 0, 0);
  }
#pragma unroll
  for (int m=0;m<4;m++){
#pragma unroll
    for (int n=0;n<4;n++){
      int col = bn + wc*64 + n*16 + l15;
      float bcol = bias[col];
#pragma unroll
      for (int r=0;r<4;r++){
        int row = bm + wr*64 + m*16 + (lane>>4)*4 + r;
        if (row < M){
          float val = acc[m][n][r] + bcol;
          if (BOUT) ((unsigned short*)Cout)[(size_t)row*N + col] = f2bf(val);
          else      ((float*)Cout)[(size_t)row*N + col] = val;
        }
      }
    }
  }
}

// ---------------- split-K fp32 GEMM to partial slabs (no atomics) ----------------
__global__ __launch_bounds__(256) void sgemm_partial(
    const float* __restrict__ A, const float* __restrict__ W,
    float* __restrict__ P, int M, int N, int K, int kchunk, int zoff)
{
  __shared__ float As[32][68];
  __shared__ __align__(16) float Bs[32][64];
  int tid = threadIdx.x;
  int bm = blockIdx.y*64, bn = blockIdx.x*64;
  int kbeg = blockIdx.z*kchunk;
  int kend = min(kbeg + kchunk, K);
  float* Pz = P + (size_t)(zoff + blockIdx.z)*M*N;
  int ty = tid >> 4, tx = tid & 15;
  float acc[4][4] = {};
  for (int k0 = kbeg; k0 < kend; k0 += 32){
#pragma unroll
    for (int i=0;i<2;i++){
      int lin = tid + i*256;
      int r = lin >> 3;
      int kq = (lin & 7) * 4;
      float4 av = make_float4(0.f,0.f,0.f,0.f);
      int row = bm + r;
      if (row < M) av = *reinterpret_cast<const float4*>(A + (size_t)row*K + k0 + kq);
      As[kq+0][r]=av.x; As[kq+1][r]=av.y; As[kq+2][r]=av.z; As[kq+3][r]=av.w;
    }
#pragma unroll
    for (int i=0;i<2;i++){
      int lin = tid + i*256;
      int kr = lin >> 4;
      int c4 = (lin & 15) * 4;
      float4 wv = *reinterpret_cast<const float4*>(W + (size_t)(k0+kr)*N + bn + c4);
      *reinterpret_cast<float4*>(&Bs[kr][c4]) = wv;
    }
    __syncthreads();
#pragma unroll
    for (int kk=0;kk<32;kk++){
      float a[4], b[4];
#pragma unroll
      for (int i=0;i<4;i++) a[i] = As[kk][ty*4+i];
#pragma unroll
      for (int j=0;j<4;j++) b[j] = Bs[kk][tx*4+j];
#pragma unroll
      for (int i=0;i<4;i++)
#pragma unroll
        for (int j=0;j<4;j++) acc[i][j] += a[i]*b[j];
    }
    __syncthreads();
  }
#pragma unroll
  for (int i=0;i<4;i++){
    int row = bm + ty*4 + i;
    if (row >= M) break;
#pragma unroll
    for (int j=0;j<4;j++)
      Pz[(size_t)row*N + bn + tx*4 + j] = acc[i][j];
  }
}

// ---------------- O[t] = bias[t&nmask] + sum_z P[z][t] ----------------
__global__ __launch_bounds__(256) void reduce_add_kernel(
    const float* __restrict__ P, const float* __restrict__ bias,
    float* __restrict__ O, int total, int nz, int nmask)
{
  int t = blockIdx.x*256 + threadIdx.x;
  if (t >= total) return;
  float s = bias[t & nmask];
  for (int z = 0; z < nz; ++z) s += P[(size_t)z*total + t];
  O[t] = s;
}

// ---------------- mean pool (bf16 in, fp32 out) ----------------
__global__ __launch_bounds__(256) void pool_kernel(const unsigned short* __restrict__ h2,
                                                   float* __restrict__ g)
{
  int t = blockIdx.x*256 + threadIdx.x;
  if (t >= NB*256) return;
  int b = t >> 8, f4 = (t & 255) * 4;
  float4 s = make_float4(0.f,0.f,0.f,0.f);
#pragma unroll
  for (int i=0;i<NPG;i++){
    ushort4 v = *reinterpret_cast<const ushort4*>(h2 + (size_t)(b*NPG+i)*1024 + f4);
    s.x += bf2f(v.x); s.y += bf2f(v.y); s.z += bf2f(v.z); s.w += bf2f(v.w);
  }
  s.x *= (1.0f/NPG); s.y *= (1.0f/NPG); s.z *= (1.0f/NPG); s.w *= (1.0f/NPG);
  *reinterpret_cast<float4*>(g + (size_t)b*1024 + f4) = s;
}

extern "C" void kernel_launch(void* const* d_in, const int* in_sizes, int n_in,
                              void* d_out, int out_size, void* d_ws, size_t ws_size,
                              hipStream_t stream)
{
  const float* x    = (const float*)d_in[0];
  const int*   ei   = (const int*)d_in[1];
  const float* ea   = (const float*)d_in[2];
  const float* fpb  = (const float*)d_in[4];
  const float* Wq1  = (const float*)d_in[5];  const float* bq1 = (const float*)d_in[6];
  const float* Wk1  = (const float*)d_in[7];  const float* bk1 = (const float*)d_in[8];
  const float* Wv1  = (const float*)d_in[9];  const float* bv1 = (const float*)d_in[10];
  const float* We1  = (const float*)d_in[11];
  const float* Ws1  = (const float*)d_in[12]; const float* bs1 = (const float*)d_in[13];
  const float* Wq2  = (const float*)d_in[14]; const float* bq2 = (const float*)d_in[15];
  const float* Wk2  = (const float*)d_in[16]; const float* bk2 = (const float*)d_in[17];
  const float* Wv2  = (const float*)d_in[18]; const float* bv2 = (const float*)d_in[19];
  const float* We2  = (const float*)d_in[20];
  const float* Ws2  = (const float*)d_in[21]; const float* bs2 = (const float*)d_in[22];
  const float* Wfp  = (const float*)d_in[23]; const float* bfp = (const float*)d_in[24];
  const float* Wfin = (const float*)d_in[25]; const float* bfin= (const float*)d_in[26];
  const int* src = ei;
  const int* dst = ei + NE;
  float* out = (float*)d_out;

  // ---- workspace layout (~255 MB peak, time-disjoint aliasing) ----
  const size_t F512  = (size_t)NN*512;
  const size_t F1024 = (size_t)NN*1024;
  float* base = (float*)d_ws;
  float* C_a = base;                    // q1b/v1b; q2b/v2b (bf16); hb at +F1024 ushorts; P1/P2
  float* C_b = base + F1024;            // k2b / s2b (bf16)
  float* H   = base + 2*F1024;          // k1b / s1b (bf16); later Wt (bf16)
  unsigned short* q1b = (unsigned short*)C_a;        // [NN,512]
  unsigned short* v1b = (unsigned short*)C_a;        // [NN,512] (q1b dead)
  unsigned short* k1b = (unsigned short*)H;          // [NN,512]
  unsigned short* s1b = (unsigned short*)H;          // [NN,512] bf16 (k1b dead)
  unsigned short* hb  = (unsigned short*)C_a + F1024;   // [MPAD,512] bf16
  unsigned short* q2b = (unsigned short*)C_a;        // [NN,1024] bf16
  unsigned short* k2b = (unsigned short*)C_b;        // [NN,1024] bf16
  unsigned short* v2b = (unsigned short*)C_a;        // [NN,1024] bf16 (q2b dead)
  unsigned short* s2b = (unsigned short*)C_b;        // [NN,1024] bf16 (k2b dead)
  unsigned short* WtQ = (unsigned short*)H;          // 4 x [1024,512] bf16 (s1b dead)
  unsigned short* WtK = WtQ + (size_t)1024*512;
  unsigned short* WtV = WtK + (size_t)1024*512;
  unsigned short* WtS = WtV + (size_t)1024*512;
  float* P1 = C_a;                            // 5 x [NB*1024]
  float* P2 = C_a + 5*(size_t)NB*1024;        // 8 x [NB*256]

  float* tail = base + 2*F1024 + F512;
  float*    alphab   = tail;                                  // NE*4 (normalized weights)
  unsigned* deg      = (unsigned*)(alphab + (size_t)NE*4);    // NN
  unsigned* cur      = deg + NN;                              // NN
  unsigned* rowstart = cur + NN;                              // NN+1
  int*      eidx     = (int*)(rowstart + NN + 1);             // NE
  float*    g        = (float*)(eidx + NE);                   // NB*1024
  float*    fp       = g + (size_t)NB*1024;                   // NB*256

  // ================= CSR build =================
  hipMemsetAsync(deg, 0, sizeof(unsigned)*NN, stream);
  hipMemsetAsync(cur, 0, sizeof(unsigned)*NN, stream);
  count_kernel<<<(NE+255)/256, 256, 0, stream>>>(dst, deg);
  scan_kernel<<<1, 1024, 0, stream>>>(deg, rowstart);
  scatter_kernel<<<(NE+255)/256, 256, 0, stream>>>(dst, rowstart, cur, eidx);

  // ================= Layer 1 =================
  node_gemm_l1_pair<true,true><<<(NN*512+255)/256, 256, 0, stream>>>(
      x, Wq1,bq1, Wk1,bk1, q1b, k1b);
  alpha_fused512<<<(NN*64+255)/256, 256, 0, stream>>>(
      q1b, k1b, ea, We1, src, rowstart, eidx, alphab);
  node_gemm_l1_pair<true,true><<<(NN*512+255)/256, 256, 0, stream>>>(
      x, Wv1,bv1, Ws1,bs1, v1b, s1b);
  gather512_kernel<<<NN, 256, 0, stream>>>(v1b, ea, We1, src, rowstart, eidx,
                                           alphab, s1b, hb);
  hipMemsetAsync(hb + F512, 0, (size_t)(MPAD-NN)*512*sizeof(unsigned short), stream);

  // ================= weights to bf16 (H free: s1b dead) =================
  cvt_wt_kernel<<<(1024*512+255)/256, 256, 0, stream>>>(Wq2, WtQ);
  cvt_wt_kernel<<<(1024*512+255)/256, 256, 0, stream>>>(Wk2, WtK);
  cvt_wt_kernel<<<(1024*512+255)/256, 256, 0, stream>>>(Wv2, WtV);
  cvt_wt_kernel<<<(1024*512+255)/256, 256, 0, stream>>>(Ws2, WtS);

  // ================= Layer 2 =================
  {
    dim3 grid(8, MPAD/128);
    gemm_bf16_mfma<true><<<grid, 256, 0, stream>>>(hb, WtQ, bq2, q2b, NN);   // q2 bf16
    gemm_bf16_mfma<true><<<grid, 256, 0, stream>>>(hb, WtK, bk2, k2b, NN);   // k2 bf16
  }
  alpha_fused1024<<<(NN*64+255)/256, 256, 0, stream>>>(
      q2b, k2b, ea, We2, src, rowstart, eidx, alphab);
  {
    dim3 grid(8, MPAD/128);
    gemm_bf16_mfma<true><<<grid, 256, 0, stream>>>(hb, WtV, bv2, v2b, NN);   // v2 bf16 (q2b dead)
    gemm_bf16_mfma<true><<<grid, 256, 0, stream>>>(hb, WtS, bs2, s2b, NN);   // s2 bf16 (k2b dead)
  }
  gather1024_kernel<<<NN, 256, 0, stream>>>(v2b, ea, We2, src, rowstart, eidx,
                                            alphab, s2b);

  // ================= pooling + head (partial split-K + reduce) =================
  pool_kernel<<<(NB*256+255)/256, 256, 0, stream>>>(s2b, g);   // C_a now dead -> P1/P2

  {
    dim3 gfp(256/64, (NB+63)/64, 8);
    sgemm_partial<<<gfp, 256, 0, stream>>>(fpb, Wfp, P2, NB, 256, 2048, 256, 0);
    reduce_add_kernel<<<(NB*256+255)/256, 256, 0, stream>>>(P2, bfp, fp, NB*256, 8, 255);
  }
  {
    dim3 g1(1024/64, (NB+63)/64, 4);
    sgemm_partial<<<g1, 256, 0, stream>>>(g, Wfin, P1, NB, 1024, 1024, 256, 0);
    dim3 g2(1024/64, (NB+63)/64, 1);
    sgemm_partial<<<g2, 256, 0, stream>>>(fp, Wfin + (size_t)1024*1024, P1, NB, 1024, 256, 256, 4);
    reduce_add_kernel<<<(NB*1024+255)/256, 256, 0, stream>>>(P1, bfin, out, NB*1024, 5, 1023);
  }
}

// Round 15
// 821.212 us; speedup vs baseline: 1.0072x; 1.0072x over previous
//
#include <hip/hip_runtime.h>
#include <cstdint>
#include <cstddef>

static constexpr int NN = 24000;   // nodes
static constexpr int NE = 96000;   // edges
static constexpr int NB = 1200;    // graphs
static constexpr int NPG = 20;     // nodes per graph
static constexpr int MPAD = 24064; // NN padded to 128

typedef __attribute__((ext_vector_type(8))) short bfv8;
typedef __attribute__((ext_vector_type(4))) float fv4;

// ---- ordered-uint mapping for float atomicMax (memset 0 == -inf) ----
__device__ __forceinline__ unsigned f2ord(float f){
  unsigned u = __float_as_uint(f);
  return (u & 0x80000000u) ? ~u : (u | 0x80000000u);
}
__device__ __forceinline__ float ord2f(unsigned u){
  return (u & 0x80000000u) ? __uint_as_float(u & 0x7FFFFFFFu)
                           : __uint_as_float(~u);
}
__device__ __forceinline__ unsigned short f2bf(float f){
  unsigned u = __float_as_uint(f);
  u += 0x7FFFu + ((u >> 16) & 1u);   // RNE
  return (unsigned short)(u >> 16);
}
__device__ __forceinline__ float bf2f(unsigned short s){
  return __uint_as_float(((unsigned)s) << 16);
}

// ---------------- CSR build ----------------
__global__ __launch_bounds__(256) void count_kernel(const int* __restrict__ dst,
                                                    unsigned* __restrict__ deg)
{
  int e = blockIdx.x*256 + threadIdx.x;
  if (e < NE) atomicAdd(&deg[dst[e]], 1u);
}

__global__ __launch_bounds__(1024) void scan_kernel(const unsigned* __restrict__ deg,
                                                    unsigned* __restrict__ rowstart)
{
  __shared__ unsigned s[1024];
  __shared__ unsigned carry_s;
  int tid = threadIdx.x;
  if (tid == 0) carry_s = 0;
  __syncthreads();
  for (int base = 0; base < NN; base += 1024){
    unsigned v = (base + tid < NN) ? deg[base + tid] : 0u;
    s[tid] = v;
    __syncthreads();
#pragma unroll
    for (int off = 1; off < 1024; off <<= 1){
      unsigned t = (tid >= off) ? s[tid - off] : 0u;
      __syncthreads();
      s[tid] += t;
      __syncthreads();
    }
    unsigned carry = carry_s;
    if (base + tid < NN) rowstart[base + tid] = carry + s[tid] - v;
    __syncthreads();
    if (tid == 0) carry_s = carry + s[1023];
    __syncthreads();
  }
  if (tid == 0) rowstart[NN] = carry_s;
}

__global__ __launch_bounds__(256) void scatter_kernel(const int* __restrict__ dst,
                                                      const unsigned* __restrict__ rowstart,
                                                      unsigned* __restrict__ cur,
                                                      int* __restrict__ eidx)
{
  int e = blockIdx.x*256 + threadIdx.x;
  if (e >= NE) return;
  int d = dst[e];
  unsigned p = rowstart[d] + atomicAdd(&cur[d], 1u);
  eidx[p] = e;
}

// ---------------- layer-1 node projections (K=9), two outputs per pass ----------------
template<bool BA, bool BB>
__global__ __launch_bounds__(256) void node_gemm_l1_pair(
    const float* __restrict__ x,
    const float* __restrict__ Wa, const float* __restrict__ ba,
    const float* __restrict__ Wb, const float* __restrict__ bb,
    void* __restrict__ outa, void* __restrict__ outb)
{
  int t = blockIdx.x*256 + threadIdx.x;
  if (t >= NN*512) return;
  int n = t >> 9, j = t & 511;
  float xr[9];
#pragma unroll
  for (int i=0;i<9;i++) xr[i] = x[n*9+i];
  float aa=ba[j], ab=bb[j];
#pragma unroll
  for (int i=0;i<9;i++){
    float xi = xr[i];
    aa += xi*Wa[i*512+j];
    ab += xi*Wb[i*512+j];
  }
  if (BA) ((unsigned short*)outa)[t] = f2bf(aa); else ((float*)outa)[t] = aa;
  if (BB) ((unsigned short*)outb)[t] = f2bf(ab); else ((float*)outb)[t] = ab;
}

// ---------------- L1 attention scores (bf16 q/k, HC=512): one wave per CSR slot ----------------
// Edges visited in dst-sorted order via eidx -> q/k row reuse hits L1/L2.
__global__ __launch_bounds__(256) void alpha_bf16_hc512(
    const unsigned short* __restrict__ q, const unsigned short* __restrict__ k,
    const float* __restrict__ ea, const float* __restrict__ We,
    const int* __restrict__ src, const int* __restrict__ dst,
    const int* __restrict__ eidx,
    float* __restrict__ alpha, unsigned* __restrict__ amax)
{
  int wave = (blockIdx.x*256 + threadIdx.x) >> 6;
  int lane = threadIdx.x & 63;
  if (wave >= NE) return;
  int e = eidx[wave];
  int s = src[e], d = dst[e];
  float ea0=ea[e*4+0], ea1=ea[e*4+1], ea2=ea[e*4+2], ea3=ea[e*4+3];
  const float scale = 0.088388347648318447f;   // 1/sqrt(128)
  int off = lane*8;
  bfv8 qv = *reinterpret_cast<const bfv8*>(q + (size_t)d*512 + off);
  bfv8 kv = *reinterpret_cast<const bfv8*>(k + (size_t)s*512 + off);
  float part = 0.f;
#pragma unroll
  for (int j=0;j<8;j++){
    int f = off + j;
    float ef = ea0*We[f] + ea1*We[512+f] + ea2*We[1024+f] + ea3*We[1536+f];
    part += bf2f((unsigned short)qv[j]) * (bf2f((unsigned short)kv[j]) + ef);
  }
#pragma unroll
  for (int o=8; o>=1; o>>=1) part += __shfl_xor(part, o);  // per-16-lane group
  if ((lane & 15) == 0){
    int h = lane >> 4;
    float a = part*scale;
    alpha[e*4+h] = a;
    atomicMax(&amax[d*4+h], f2ord(a));
  }
}

// ---------------- L2 attention scores (bf16 q/k, HC=1024): one wave per CSR slot ----------------
__global__ __launch_bounds__(256) void alpha_bf16_hc1024(
    const unsigned short* __restrict__ q, const unsigned short* __restrict__ k,
    const float* __restrict__ ea, const float* __restrict__ We,
    const int* __restrict__ src, const int* __restrict__ dst,
    const int* __restrict__ eidx,
    float* __restrict__ alpha, unsigned* __restrict__ amax)
{
  int wave = (blockIdx.x*256 + threadIdx.x) >> 6;
  int lane = threadIdx.x & 63;
  if (wave >= NE) return;
  int e = eidx[wave];
  int s = src[e], d = dst[e];
  float ea0=ea[e*4+0], ea1=ea[e*4+1], ea2=ea[e*4+2], ea3=ea[e*4+3];
  const float scale = 1.0f/16.0f;   // 1/sqrt(256)
#pragma unroll
  for (int p=0;p<2;p++){
    int off = p*512 + lane*8;
    bfv8 qv = *reinterpret_cast<const bfv8*>(q + (size_t)d*1024 + off);
    bfv8 kv = *reinterpret_cast<const bfv8*>(k + (size_t)s*1024 + off);
    float part = 0.f;
#pragma unroll
    for (int j=0;j<8;j++){
      int f = off + j;
      float ef = ea0*We[f] + ea1*We[1024+f] + ea2*We[2048+f] + ea3*We[3072+f];
      part += bf2f((unsigned short)qv[j]) * (bf2f((unsigned short)kv[j]) + ef);
    }
#pragma unroll
    for (int o=16; o>=1; o>>=1) part += __shfl_xor(part, o);  // reduce 32-lane half
    if ((lane & 31) == 0){
      int h = p*2 + (lane>>5);
      float a = part*scale;
      alpha[e*4+h] = a;
      atomicMax(&amax[d*4+h], f2ord(a));
    }
  }
}

// ---------------- exp + denominator ----------------
__global__ __launch_bounds__(256) void ex_kernel(
    float* __restrict__ alpha, const unsigned* __restrict__ amax,
    const int* __restrict__ dst, float* __restrict__ den)
{
  int t = blockIdx.x*256 + threadIdx.x;
  if (t >= NE*4) return;
  int e = t>>2, h = t&3;
  int d = dst[e];
  float m = ord2f(amax[d*4+h]);
  float v = __expf(alpha[t]-m);
  alpha[t] = v;
  unsafeAtomicAdd(&den[d*4+h], v);
}

// ---------------- CSR gather L1: bf16 v, bf16 s1 init, bf16 relu'd output ----------------
__global__ __launch_bounds__(256) void gather512_kernel(
    const unsigned short* __restrict__ v, const float* __restrict__ ea,
    const float* __restrict__ We,
    const int* __restrict__ src,
    const unsigned* __restrict__ rowstart, const int* __restrict__ eidx,
    const float* __restrict__ exw, const float* __restrict__ den,
    const unsigned short* __restrict__ accin, unsigned short* __restrict__ hb)
{
  int n = blockIdx.x;
  int tid = threadIdx.x;
  int h = tid >> 6;
  int f2 = tid*2;
  unsigned p0 = rowstart[n], p1 = rowstart[n+1];
  float2 W0 = *reinterpret_cast<const float2*>(We + 0*512 + f2);
  float2 W1 = *reinterpret_cast<const float2*>(We + 1*512 + f2);
  float2 W2 = *reinterpret_cast<const float2*>(We + 2*512 + f2);
  float2 W3 = *reinterpret_cast<const float2*>(We + 3*512 + f2);
  float rdn = 1.0f / (den[n*4+h] + 1e-16f);
  ushort2 a0 = *reinterpret_cast<const ushort2*>(accin + (size_t)n*512 + f2);
  float2 s = make_float2(bf2f(a0.x), bf2f(a0.y));
  for (unsigned p = p0; p < p1; ++p){
    int e  = eidx[p];
    float w = exw[e*4+h] * rdn;
    float4 eav = *reinterpret_cast<const float4*>(ea + (size_t)e*4);
    ushort2 vv = *reinterpret_cast<const ushort2*>(v + (size_t)src[e]*512 + f2);
    float efx = eav.x*W0.x + eav.y*W1.x + eav.z*W2.x + eav.w*W3.x;
    float efy = eav.x*W0.y + eav.y*W1.y + eav.z*W2.y + eav.w*W3.y;
    s.x += w*(bf2f(vv.x) + efx);
    s.y += w*(bf2f(vv.y) + efy);
  }
  ushort2 o;
  o.x = f2bf(fmaxf(s.x, 0.0f));
  o.y = f2bf(fmaxf(s.y, 0.0f));
  *reinterpret_cast<ushort2*>(hb + (size_t)n*512 + f2) = o;
}

// ---------------- CSR gather L2: bf16 v, bf16 acc RMW (fp32 accumulate) ----------------
__global__ __launch_bounds__(256) void gather1024_kernel(
    const unsigned short* __restrict__ v, const float* __restrict__ ea,
    const float* __restrict__ We,
    const int* __restrict__ src,
    const unsigned* __restrict__ rowstart, const int* __restrict__ eidx,
    const float* __restrict__ exw, const float* __restrict__ den,
    unsigned short* __restrict__ acc)
{
  int n = blockIdx.x;
  int tid = threadIdx.x;
  int h = tid >> 6;
  int f4 = tid*4;
  unsigned p0 = rowstart[n], p1 = rowstart[n+1];
  float4 W0 = *reinterpret_cast<const float4*>(We + 0*1024 + f4);
  float4 W1 = *reinterpret_cast<const float4*>(We + 1*1024 + f4);
  float4 W2 = *reinterpret_cast<const float4*>(We + 2*1024 + f4);
  float4 W3 = *reinterpret_cast<const float4*>(We + 3*1024 + f4);
  float rdn = 1.0f / (den[n*4+h] + 1e-16f);
  ushort4 a0 = *reinterpret_cast<const ushort4*>(acc + (size_t)n*1024 + f4);
  float4 s = make_float4(bf2f(a0.x), bf2f(a0.y), bf2f(a0.z), bf2f(a0.w));
  for (unsigned p = p0; p < p1; ++p){
    int e  = eidx[p];
    float w = exw[e*4+h] * rdn;
    float4 eav = *reinterpret_cast<const float4*>(ea + (size_t)e*4);
    ushort4 vv = *reinterpret_cast<const ushort4*>(v + (size_t)src[e]*1024 + f4);
    s.x += w*(bf2f(vv.x) + eav.x*W0.x + eav.y*W1.x + eav.z*W2.x + eav.w*W3.x);
    s.y += w*(bf2f(vv.y) + eav.x*W0.y + eav.y*W1.y + eav.z*W2.y + eav.w*W3.y);
    s.z += w*(bf2f(vv.z) + eav.x*W0.z + eav.y*W1.z + eav.z*W2.z + eav.w*W3.z);
    s.w += w*(bf2f(vv.w) + eav.x*W0.w + eav.y*W1.w + eav.z*W2.w + eav.w*W3.w);
  }
  ushort4 o;
  o.x = f2bf(s.x); o.y = f2bf(s.y); o.z = f2bf(s.z); o.w = f2bf(s.w);
  *reinterpret_cast<ushort4*>(acc + (size_t)n*1024 + f4) = o;
}

// ---------------- W[512,1024] -> Wt[1024,512] bf16 ----------------
__global__ __launch_bounds__(256) void cvt_wt_kernel(const float* __restrict__ W,
                                                     unsigned short* __restrict__ Wt)
{
  int t = blockIdx.x*256 + threadIdx.x;
  if (t >= 1024*512) return;
  int n = t >> 9, k = t & 511;
  Wt[t] = f2bf(W[k*1024 + n]);
}

// ---------------- bf16 MFMA GEMM: out[M,1024] = A[MPAD,512]@Wt^T + bias ----------------
template<bool BOUT>
__global__ __launch_bounds__(256) void gemm_bf16_mfma(
    const unsigned short* __restrict__ A,
    const unsigned short* __restrict__ B,   // Wt
    const float* __restrict__ bias,
    void* __restrict__ Cout, int M)
{
  constexpr int K = 512, N = 1024;
  __shared__ unsigned short As[128*32];
  __shared__ unsigned short Bs[128*32];
  int tid  = threadIdx.x;
  int wid  = tid >> 6, lane = tid & 63;
  int wr   = wid >> 1, wc = wid & 1;
  int bm   = blockIdx.y * 128, bn = blockIdx.x * 128;
  int l15  = lane & 15, kg = lane >> 4;

  int r0 = (wid*2+0)*16 + (lane>>2);
  int r1 = (wid*2+1)*16 + (lane>>2);
  int s0 = lane & 3;
  int kc0 = s0 ^ ((r0>>1)&3);
  int kc1 = s0 ^ ((r1>>1)&3);
  unsigned short* ldsA0 = As + (wid*2+0)*512;
  unsigned short* ldsA1 = As + (wid*2+1)*512;
  unsigned short* ldsB0 = Bs + (wid*2+0)*512;
  unsigned short* ldsB1 = Bs + (wid*2+1)*512;

  fv4 acc[4][4];
#pragma unroll
  for (int m=0;m<4;m++)
#pragma unroll
    for (int n=0;n<4;n++) acc[m][n] = (fv4){0.f,0.f,0.f,0.f};

  for (int k0 = 0; k0 < K; k0 += 32){
    __syncthreads();
    __builtin_amdgcn_global_load_lds(
        (const __attribute__((address_space(1))) void*)(A + (size_t)(bm+r0)*K + k0 + kc0*8),
        (__attribute__((address_space(3))) void*)ldsA0, 16, 0, 0);
    __builtin_amdgcn_global_load_lds(
        (const __attribute__((address_space(1))) void*)(A + (size_t)(bm+r1)*K + k0 + kc1*8),
        (__attribute__((address_space(3))) void*)ldsA1, 16, 0, 0);
    __builtin_amdgcn_global_load_lds(
        (const __attribute__((address_space(1))) void*)(B + (size_t)(bn+r0)*K + k0 + kc0*8),
        (__attribute__((address_space(3))) void*)ldsB0, 16, 0, 0);
    __builtin_amdgcn_global_load_lds(
        (const __attribute__((address_space(1))) void*)(B + (size_t)(bn+r1)*K + k0 + kc1*8),
        (__attribute__((address_space(3))) void*)ldsB1, 16, 0, 0);
    __syncthreads();
    bfv8 af[4], bfr[4];
#pragma unroll
    for (int m=0;m<4;m++){
      int r  = wr*64 + m*16 + l15;
      int sl = kg ^ ((r>>1)&3);
      af[m] = *reinterpret_cast<const bfv8*>(reinterpret_cast<char*>(As) + r*64 + sl*16);
    }
#pragma unroll
    for (int n=0;n<4;n++){
      int r  = wc*64 + n*16 + l15;
      int sl = kg ^ ((r>>1)&3);
      bfr[n] = *reinterpret_cast<const bfv8*>(reinterpret_cast<char*>(Bs) + r*64 + sl*16);
    }
#pragma unroll
    for (int m=0;m<4;m++)
#pragma unroll
      for (int n=0;n<4;n++)
        acc[m][n] = __builtin_amdgcn_mfma_f32_16x16x32_bf16(af[m], bfr[n], acc[m][n], 0, 0, 0);
  }
#pragma unroll
  for (int m=0;m<4;m++){
#pragma unroll
    for (int n=0;n<4;n++){
      int col = bn + wc*64 + n*16 + l15;
      float bcol = bias[col];
#pragma unroll
      for (int r=0;r<4;r++){
        int row = bm + wr*64 + m*16 + (lane>>4)*4 + r;
        if (row < M){
          float val = acc[m][n][r] + bcol;
          if (BOUT) ((unsigned short*)Cout)[(size_t)row*N + col] = f2bf(val);
          else      ((float*)Cout)[(size_t)row*N + col] = val;
        }
      }
    }
  }
}

// ---------------- split-K fp32 GEMM to partial slabs (no atomics) ----------------
__global__ __launch_bounds__(256) void sgemm_partial(
    const float* __restrict__ A, const float* __restrict__ W,
    float* __restrict__ P, int M, int N, int K, int kchunk, int zoff)
{
  __shared__ float As[32][68];
  __shared__ __align__(16) float Bs[32][64];
  int tid = threadIdx.x;
  int bm = blockIdx.y*64, bn = blockIdx.x*64;
  int kbeg = blockIdx.z*kchunk;
  int kend = min(kbeg + kchunk, K);
  float* Pz = P + (size_t)(zoff + blockIdx.z)*M*N;
  int ty = tid >> 4, tx = tid & 15;
  float acc[4][4] = {};
  for (int k0 = kbeg; k0 < kend; k0 += 32){
#pragma unroll
    for (int i=0;i<2;i++){
      int lin = tid + i*256;
      int r = lin >> 3;
      int kq = (lin & 7) * 4;
      float4 av = make_float4(0.f,0.f,0.f,0.f);
      int row = bm + r;
      if (row < M) av = *reinterpret_cast<const float4*>(A + (size_t)row*K + k0 + kq);
      As[kq+0][r]=av.x; As[kq+1][r]=av.y; As[kq+2][r]=av.z; As[kq+3][r]=av.w;
    }
#pragma unroll
    for (int i=0;i<2;i++){
      int lin = tid + i*256;
      int kr = lin >> 4;
      int c4 = (lin & 15) * 4;
      float4 wv = *reinterpret_cast<const float4*>(W + (size_t)(k0+kr)*N + bn + c4);
      *reinterpret_cast<float4*>(&Bs[kr][c4]) = wv;
    }
    __syncthreads();
#pragma unroll
    for (int kk=0;kk<32;kk++){
      float a[4], b[4];
#pragma unroll
      for (int i=0;i<4;i++) a[i] = As[kk][ty*4+i];
#pragma unroll
      for (int j=0;j<4;j++) b[j] = Bs[kk][tx*4+j];
#pragma unroll
      for (int i=0;i<4;i++)
#pragma unroll
        for (int j=0;j<4;j++) acc[i][j] += a[i]*b[j];
    }
    __syncthreads();
  }
#pragma unroll
  for (int i=0;i<4;i++){
    int row = bm + ty*4 + i;
    if (row >= M) break;
#pragma unroll
    for (int j=0;j<4;j++)
      Pz[(size_t)row*N + bn + tx*4 + j] = acc[i][j];
  }
}

// ---------------- O[t] = bias[t&nmask] + sum_z P[z][t] ----------------
__global__ __launch_bounds__(256) void reduce_add_kernel(
    const float* __restrict__ P, const float* __restrict__ bias,
    float* __restrict__ O, int total, int nz, int nmask)
{
  int t = blockIdx.x*256 + threadIdx.x;
  if (t >= total) return;
  float s = bias[t & nmask];
  for (int z = 0; z < nz; ++z) s += P[(size_t)z*total + t];
  O[t] = s;
}

// ---------------- mean pool (bf16 in, fp32 out) ----------------
__global__ __launch_bounds__(256) void pool_kernel(const unsigned short* __restrict__ h2,
                                                   float* __restrict__ g)
{
  int t = blockIdx.x*256 + threadIdx.x;
  if (t >= NB*256) return;
  int b = t >> 8, f4 = (t & 255) * 4;
  float4 s = make_float4(0.f,0.f,0.f,0.f);
#pragma unroll
  for (int i=0;i<NPG;i++){
    ushort4 v = *reinterpret_cast<const ushort4*>(h2 + (size_t)(b*NPG+i)*1024 + f4);
    s.x += bf2f(v.x); s.y += bf2f(v.y); s.z += bf2f(v.z); s.w += bf2f(v.w);
  }
  s.x *= (1.0f/NPG); s.y *= (1.0f/NPG); s.z *= (1.0f/NPG); s.w *= (1.0f/NPG);
  *reinterpret_cast<float4*>(g + (size_t)b*1024 + f4) = s;
}

extern "C" void kernel_launch(void* const* d_in, const int* in_sizes, int n_in,
                              void* d_out, int out_size, void* d_ws, size_t ws_size,
                              hipStream_t stream)
{
  const float* x    = (const float*)d_in[0];
  const int*   ei   = (const int*)d_in[1];
  const float* ea   = (const float*)d_in[2];
  const float* fpb  = (const float*)d_in[4];
  const float* Wq1  = (const float*)d_in[5];  const float* bq1 = (const float*)d_in[6];
  const float* Wk1  = (const float*)d_in[7];  const float* bk1 = (const float*)d_in[8];
  const float* Wv1  = (const float*)d_in[9];  const float* bv1 = (const float*)d_in[10];
  const float* We1  = (const float*)d_in[11];
  const float* Ws1  = (const float*)d_in[12]; const float* bs1 = (const float*)d_in[13];
  const float* Wq2  = (const float*)d_in[14]; const float* bq2 = (const float*)d_in[15];
  const float* Wk2  = (const float*)d_in[16]; const float* bk2 = (const float*)d_in[17];
  const float* Wv2  = (const float*)d_in[18]; const float* bv2 = (const float*)d_in[19];
  const float* We2  = (const float*)d_in[20];
  const float* Ws2  = (const float*)d_in[21]; const float* bs2 = (const float*)d_in[22];
  const float* Wfp  = (const float*)d_in[23]; const float* bfp = (const float*)d_in[24];
  const float* Wfin = (const float*)d_in[25]; const float* bfin= (const float*)d_in[26];
  const int* src = ei;
  const int* dst = ei + NE;
  float* out = (float*)d_out;

  // ---- workspace layout (~255 MB peak, time-disjoint aliasing) ----
  const size_t F512  = (size_t)NN*512;
  const size_t F1024 = (size_t)NN*1024;
  float* base = (float*)d_ws;
  float* C_a = base;                    // q1b/v1b; q2b/v2b (bf16); hb at +F1024 ushorts; P1/P2
  float* C_b = base + F1024;            // k2b / s2b (bf16)
  float* H   = base + 2*F1024;          // k1b / s1b (bf16); later Wt (bf16)
  unsigned short* q1b = (unsigned short*)C_a;        // [NN,512]
  unsigned short* v1b = (unsigned short*)C_a;        // [NN,512] (q1b dead)
  unsigned short* k1b = (unsigned short*)H;          // [NN,512]
  unsigned short* s1b = (unsigned short*)H;          // [NN,512] bf16 (k1b dead)
  unsigned short* hb  = (unsigned short*)C_a + F1024;   // [MPAD,512] bf16
  unsigned short* q2b = (unsigned short*)C_a;        // [NN,1024] bf16
  unsigned short* k2b = (unsigned short*)C_b;        // [NN,1024] bf16
  unsigned short* v2b = (unsigned short*)C_a;        // [NN,1024] bf16 (q2b dead)
  unsigned short* s2b = (unsigned short*)C_b;        // [NN,1024] bf16 (k2b dead)
  unsigned short* WtQ = (unsigned short*)H;          // 4 x [1024,512] bf16 (s1b dead)
  unsigned short* WtK = WtQ + (size_t)1024*512;
  unsigned short* WtV = WtK + (size_t)1024*512;
  unsigned short* WtS = WtV + (size_t)1024*512;
  float* P1 = C_a;                            // 5 x [NB*1024]
  float* P2 = C_a + 5*(size_t)NB*1024;        // 8 x [NB*256]

  float* tail = base + 2*F1024 + F512;
  float*    alphab   = tail;                                  // NE*4 (scores -> exp)
  unsigned* amax     = (unsigned*)(alphab + (size_t)NE*4);    // NN*4
  float*    den      = (float*)(amax + (size_t)NN*4);         // NN*4
  unsigned* deg      = (unsigned*)(den + (size_t)NN*4);       // NN
  unsigned* cur      = deg + NN;                              // NN
  unsigned* rowstart = cur + NN;                              // NN+1
  int*      eidx     = (int*)(rowstart + NN + 1);             // NE
  float*    g        = (float*)(eidx + NE);                   // NB*1024
  float*    fp       = g + (size_t)NB*1024;                   // NB*256

  // ================= CSR build =================
  hipMemsetAsync(deg, 0, sizeof(unsigned)*NN, stream);
  hipMemsetAsync(cur, 0, sizeof(unsigned)*NN, stream);
  count_kernel<<<(NE+255)/256, 256, 0, stream>>>(dst, deg);
  scan_kernel<<<1, 1024, 0, stream>>>(deg, rowstart);
  scatter_kernel<<<(NE+255)/256, 256, 0, stream>>>(dst, rowstart, cur, eidx);

  // ================= Layer 1 =================
  hipMemsetAsync(amax, 0, sizeof(unsigned)*(size_t)NN*4, stream);
  hipMemsetAsync(den,  0, sizeof(float)*(size_t)NN*4, stream);

  node_gemm_l1_pair<true,true><<<(NN*512+255)/256, 256, 0, stream>>>(
      x, Wq1,bq1, Wk1,bk1, q1b, k1b);
  alpha_bf16_hc512<<<NE/4, 256, 0, stream>>>(q1b, k1b, ea, We1, src, dst, eidx,
                                             alphab, amax);
  ex_kernel<<<(NE*4+255)/256, 256, 0, stream>>>(alphab, amax, dst, den);
  node_gemm_l1_pair<true,true><<<(NN*512+255)/256, 256, 0, stream>>>(
      x, Wv1,bv1, Ws1,bs1, v1b, s1b);
  gather512_kernel<<<NN, 256, 0, stream>>>(v1b, ea, We1, src, rowstart, eidx,
                                           alphab, den, s1b, hb);
  hipMemsetAsync(hb + F512, 0, (size_t)(MPAD-NN)*512*sizeof(unsigned short), stream);

  // ================= weights to bf16 (H free: s1b dead) =================
  cvt_wt_kernel<<<(1024*512+255)/256, 256, 0, stream>>>(Wq2, WtQ);
  cvt_wt_kernel<<<(1024*512+255)/256, 256, 0, stream>>>(Wk2, WtK);
  cvt_wt_kernel<<<(1024*512+255)/256, 256, 0, stream>>>(Wv2, WtV);
  cvt_wt_kernel<<<(1024*512+255)/256, 256, 0, stream>>>(Ws2, WtS);

  // ================= Layer 2 =================
  hipMemsetAsync(amax, 0, sizeof(unsigned)*(size_t)NN*4, stream);
  hipMemsetAsync(den,  0, sizeof(float)*(size_t)NN*4, stream);

  {
    dim3 grid(8, MPAD/128);
    gemm_bf16_mfma<true><<<grid, 256, 0, stream>>>(hb, WtQ, bq2, q2b, NN);   // q2 bf16
    gemm_bf16_mfma<true><<<grid, 256, 0, stream>>>(hb, WtK, bk2, k2b, NN);   // k2 bf16
  }
  alpha_bf16_hc1024<<<NE/4, 256, 0, stream>>>(q2b, k2b, ea, We2, src, dst, eidx,
                                              alphab, amax);
  ex_kernel<<<(NE*4+255)/256, 256, 0, stream>>>(alphab, amax, dst, den);
  {
    dim3 grid(8, MPAD/128);
    gemm_bf16_mfma<true><<<grid, 256, 0, stream>>>(hb, WtV, bv2, v2b, NN);   // v2 bf16 (q2b dead)
    gemm_bf16_mfma<true><<<grid, 256, 0, stream>>>(hb, WtS, bs2, s2b, NN);   // s2 bf16 (k2b dead)
  }
  gather1024_kernel<<<NN, 256, 0, stream>>>(v2b, ea, We2, src, rowstart, eidx,
                                            alphab, den, s2b);

  // ================= pooling + head (partial split-K + reduce) =================
  pool_kernel<<<(NB*256+255)/256, 256, 0, stream>>>(s2b, g);   // C_a now dead -> P1/P2

  {
    dim3 gfp(256/64, (NB+63)/64, 8);
    sgemm_partial<<<gfp, 256, 0, stream>>>(fpb, Wfp, P2, NB, 256, 2048, 256, 0);
    reduce_add_kernel<<<(NB*256+255)/256, 256, 0, stream>>>(P2, bfp, fp, NB*256, 8, 255);
  }
  {
    dim3 g1(1024/64, (NB+63)/64, 4);
    sgemm_partial<<<g1, 256, 0, stream>>>(g, Wfin, P1, NB, 1024, 1024, 256, 0);
    dim3 g2(1024/64, (NB+63)/64, 1);
    sgemm_partial<<<g2, 256, 0, stream>>>(fp, Wfin + (size_t)1024*1024, P1, NB, 1024, 256, 256, 4);
    reduce_add_kernel<<<(NB*1024+255)/256, 256, 0, stream>>>(P1, bfin, out, NB*1024, 5, 1023);
  }
}